// Round 5
// baseline (666.044 us; speedup 1.0000x reference)
//
#include <hip/hip_runtime.h>
#include <hip/hip_bf16.h>

// LiteMSA pipeline, MI355X gfx950.
// B=16, Cin=256, Cqkv=768, H=W=64 (P=4096), heads=64 (24 ch: q8,k8,v8),
// out 512 ch -> proj 256 ch + BN. Output y fp32.
//
// Numerics: the only >1e-5 hazard is the degenerate-denominator relu(q) sign
// flip (all q_d<=0 => out=0; one flipped sign => out=kv_num/kv_den ~7e-3,
// independent of flip epsilon). Fix: q channels (heads 0-31) carry fp32
// (qplane) from a 3-term split-bf16 MFMA (err ~2e-6), and a fixup pass
// recomputes |q|<1e-4 in fp64. Everything else is plain bf16 (noise <=1e-5
// at y; bf16 rounding preserves signs so relu decisions are unaffected).
//
// ws (256 MiB exactly):
//   qkv_bf [0,96M)    bf16 768ch
//   qplane [96M,160M) fp32 256ch (q of heads 0-31), fixup'd in place
//   agg_bf [160M,256M) bf16 768ch; k/v slots (ch%24 in [8,24)) reused by attn
//                      for the 512-ch 'out' plane: map(o)=(o/16)*24+8+(o%16)
// d_out: kvbuf 288K scratch at head; gemm_proj (last, sole d_out writer)
// overwrites all of it.

#define NB 16
#define CIN 256
#define CQKV 768
#define P4096 4096

typedef __bf16 bf16x8 __attribute__((ext_vector_type(8)));
typedef float f32x4 __attribute__((ext_vector_type(4)));

__device__ __forceinline__ ushort f2bf(float f) {
    union { float f; unsigned int u; } x; x.f = f;
    unsigned int u = x.u;
    unsigned int r = (u + 0x7FFFu + ((u >> 16) & 1u)) >> 16;
    return (ushort)r;
}
__device__ __forceinline__ float bf2f(ushort u) {
    union { unsigned int u; float f; } x; x.u = ((unsigned int)u) << 16;
    return x.f;
}

// ---------------- GEMM1: qkv = W_qkv(768x256) @ x[b](256x4096), 3-term split ----------------
// BM=BN=64, BK=32, 256 thr = 4 waves. MFMA 16x16x32 bf16.
// A-frag: m=lane&15, k=quad*8+j ; B-frag: n=lane&15, k=quad*8+j (Bs [n][k]).
// D: col=lane&15, row=quad*4+reg.
__global__ __launch_bounds__(256) void gemm_qkv(
    const float* __restrict__ A,      // 768 x 256 fp32
    const float* __restrict__ Bsrc,   // b-strided 256 x 4096 fp32
    ushort* __restrict__ Cbf,         // b-strided 768 x 4096 bf16
    float*  __restrict__ qplane)      // b-strided 256 x 4096 fp32 (q channels)
{
    const int n0 = blockIdx.x * 64;
    const int m0 = blockIdx.y * 64;
    const int b  = blockIdx.z;
    const int t  = threadIdx.x;
    const int wave = t >> 6, lane = t & 63, quad = lane >> 4, l15 = lane & 15;
    const int K = 256;

    __shared__ __align__(16) ushort AsH[64][40];
    __shared__ __align__(16) ushort AsL[64][40];
    __shared__ __align__(16) ushort BsH[64][40];
    __shared__ __align__(16) ushort BsL[64][40];

    f32x4 acc[4];
    #pragma unroll
    for (int nt = 0; nt < 4; nt++)
        #pragma unroll
        for (int r = 0; r < 4; r++) acc[nt][r] = 0.0f;

    const int am = t >> 2;
    const int ak = (t & 3) * 8;
    const int bkk = t >> 4;           // 0..15
    const int bnn = (t & 15) * 4;     // 0..60

    for (int k0 = 0; k0 < K; k0 += 32) {
        float av[8];
        *(float4*)&av[0] = *(const float4*)(A + (size_t)(m0 + am) * K + k0 + ak);
        *(float4*)&av[4] = *(const float4*)(A + (size_t)(m0 + am) * K + k0 + ak + 4);
        float4 b0f = *(const float4*)(Bsrc + ((size_t)b * K + k0 + bkk) * P4096 + n0 + bnn);
        float4 b1f = *(const float4*)(Bsrc + ((size_t)b * K + k0 + bkk + 16) * P4096 + n0 + bnn);

        __syncthreads();
        {
            union { ushort us[8]; uint4 v; } ah, al;
            #pragma unroll
            for (int i = 0; i < 8; i++) {
                ushort h = f2bf(av[i]);
                ah.us[i] = h;
                al.us[i] = f2bf(av[i] - bf2f(h));
            }
            *(uint4*)&AsH[am][ak] = ah.v;
            *(uint4*)&AsL[am][ak] = al.v;
        }
        {
            float bb0[4] = {b0f.x, b0f.y, b0f.z, b0f.w};
            float bb1[4] = {b1f.x, b1f.y, b1f.z, b1f.w};
            #pragma unroll
            for (int j = 0; j < 4; j++) {
                ushort h0 = f2bf(bb0[j]);
                BsH[bnn + j][bkk] = h0;
                BsL[bnn + j][bkk] = f2bf(bb0[j] - bf2f(h0));
                ushort h1 = f2bf(bb1[j]);
                BsH[bnn + j][bkk + 16] = h1;
                BsL[bnn + j][bkk + 16] = f2bf(bb1[j] - bf2f(h1));
            }
        }
        __syncthreads();

        bf16x8 afh = *(const bf16x8*)&AsH[wave * 16 + l15][quad * 8];
        bf16x8 afl = *(const bf16x8*)&AsL[wave * 16 + l15][quad * 8];
        #pragma unroll
        for (int nt = 0; nt < 4; nt++) {
            bf16x8 bfh = *(const bf16x8*)&BsH[nt * 16 + l15][quad * 8];
            bf16x8 bfl = *(const bf16x8*)&BsL[nt * 16 + l15][quad * 8];
            acc[nt] = __builtin_amdgcn_mfma_f32_16x16x32_bf16(afh, bfh, acc[nt], 0, 0, 0);
            acc[nt] = __builtin_amdgcn_mfma_f32_16x16x32_bf16(afl, bfh, acc[nt], 0, 0, 0);
            acc[nt] = __builtin_amdgcn_mfma_f32_16x16x32_bf16(afh, bfl, acc[nt], 0, 0, 0);
        }
    }

    #pragma unroll
    for (int nt = 0; nt < 4; nt++) {
        #pragma unroll
        for (int r = 0; r < 4; r++) {
            int row = m0 + wave * 16 + quad * 4 + r;
            int col = n0 + nt * 16 + l15;
            float v = acc[nt][r];
            Cbf[((size_t)b * CQKV + row) * P4096 + col] = f2bf(v);
            int rm = row % 24, hd = row / 24;
            if (rm < 8)
                qplane[((size_t)b * 256 + hd * 8 + rm) * P4096 + col] = v;
        }
    }
}

// ---------------- qfix: recompute |q|<1e-4 in fp64 (kills relu sign flips) ----------------
__global__ __launch_bounds__(256) void qfix_kernel(
    float* __restrict__ qplane, const float* __restrict__ w_qkv,
    const float* __restrict__ x)
{
    size_t i = (size_t)blockIdx.x * 256 + threadIdx.x;  // over 16*256*4096
    float q = qplane[i];
    if (fabsf(q) >= 1e-4f) return;
    int p   = (int)(i & 4095);
    int qch = (int)((i >> 12) & 255);
    int b   = (int)(i >> 20);
    int row = (qch >> 3) * 24 + (qch & 7);
    const float* wr = w_qkv + (size_t)row * 256;
    const float* xr = x + (size_t)b * 256 * P4096 + p;
    double s = 0.0;
    for (int c = 0; c < 256; c++)
        s += (double)wr[c] * (double)xr[(size_t)c * P4096];
    qplane[i] = (float)s;
}

// ---------------- dw 3x3 + grouped pw (bf16; feeds only heads 32-63) ----------------
__global__ __launch_bounds__(256) void dwpw_kernel(
    const ushort* __restrict__ qkv, const float* __restrict__ wdw,
    const float* __restrict__ wpw, ushort* __restrict__ agg)
{
    const int rt = blockIdx.x;    // 0..7
    const int g  = blockIdx.y;    // 0..95
    const int b  = blockIdx.z;
    const int t  = threadIdx.x;
    const int r0 = rt * 8;
    const int cg = g * 8;

    __shared__ __align__(16) float tile[8][10][72];  // data cols 4..67, halo 3 & 68
    __shared__ float wdw_s[8][9];
    __shared__ float wpw_s[8][8];

    if (t < 72) wdw_s[t / 9][t % 9] = wdw[(size_t)(cg + t / 9) * 9 + t % 9];
    else if (t < 136) { int i = (t - 72) >> 3, j = (t - 72) & 7; wpw_s[i][j] = wpw[(size_t)(cg + i) * 8 + j]; }
    if (t < 80) { int c = t / 10, rr = t % 10; tile[c][rr][3] = 0.0f; tile[c][rr][68] = 0.0f; }

    const ushort* src = qkv + ((size_t)(b * CQKV + cg)) * P4096;
    #pragma unroll
    for (int i = 0; i < 5; i++) {
        int idx = t + i * 256;               // 0..1279
        int c = idx / 160; int rem = idx - c * 160;
        int rr = rem >> 4; int nn = (rem & 15) * 4;
        int grow = r0 - 1 + rr;
        float4 v = make_float4(0.f, 0.f, 0.f, 0.f);
        if (grow >= 0 && grow < 64) {
            uint2 u = *(const uint2*)(src + (size_t)c * P4096 + grow * 64 + nn);
            v.x = bf2f((ushort)(u.x & 0xffff));
            v.y = bf2f((ushort)(u.x >> 16));
            v.z = bf2f((ushort)(u.y & 0xffff));
            v.w = bf2f((ushort)(u.y >> 16));
        }
        *(float4*)&tile[c][rr][4 + nn] = v;
    }
    __syncthreads();

    #pragma unroll
    for (int i = 0; i < 2; i++) {
        int pos = t + i * 256;
        int pr = pos >> 6, pc = pos & 63;
        float dwv[8];
        #pragma unroll
        for (int c = 0; c < 8; c++) {
            float s = 0.0f;
            #pragma unroll
            for (int dy = 0; dy < 3; dy++)
                #pragma unroll
                for (int dx = 0; dx < 3; dx++)
                    s += wdw_s[c][dy * 3 + dx] * tile[c][pr + dy][pc + 3 + dx];
            dwv[c] = s;
        }
        size_t obase = ((size_t)(b * CQKV + cg)) * P4096 + (size_t)(r0 + pr) * 64 + pc;
        #pragma unroll
        for (int oi = 0; oi < 8; oi++) {
            float s = 0.0f;
            #pragma unroll
            for (int j = 0; j < 8; j++) s += wpw_s[oi][j] * dwv[j];
            agg[obase + (size_t)oi * P4096] = f2bf(s);
        }
    }
}

// ---------------- kv[b,h,d,e] = sum_p relu(k_d)*v_e  (v_8 = 1) ----------------
__global__ __launch_bounds__(256) void kv_kernel(
    const ushort* __restrict__ qkv, const ushort* __restrict__ agg,
    float* __restrict__ kv)
{
    const int h = blockIdx.x, b = blockIdx.y, t = threadIdx.x;
    const ushort* src = (h < 32)
        ? qkv + ((size_t)(b * CQKV + h * 24)) * P4096
        : agg + ((size_t)(b * CQKV + (h - 32) * 24)) * P4096;

    float acc[72];
    #pragma unroll
    for (int i = 0; i < 72; i++) acc[i] = 0.0f;

    for (int pi = 0; pi < 16; pi++) {
        int p = t + pi * 256;
        float kvv[8], vv[8];
        #pragma unroll
        for (int d = 0; d < 8; d++) {
            float xk = bf2f(src[(size_t)(8 + d) * P4096 + p]);
            kvv[d] = xk > 0.0f ? xk : 0.0f;
        }
        #pragma unroll
        for (int e = 0; e < 8; e++) vv[e] = bf2f(src[(size_t)(16 + e) * P4096 + p]);
        #pragma unroll
        for (int d = 0; d < 8; d++) {
            #pragma unroll
            for (int e = 0; e < 8; e++) acc[d * 9 + e] += kvv[d] * vv[e];
            acc[d * 9 + 8] += kvv[d];
        }
    }

    #pragma unroll
    for (int i = 0; i < 72; i++) {
        float v = acc[i];
        #pragma unroll
        for (int off = 32; off > 0; off >>= 1) v += __shfl_xor(v, off, 64);
        acc[i] = v;
    }
    __shared__ float part[4][72];
    int wave = t >> 6, lane = t & 63;
    if (lane == 0) {
        #pragma unroll
        for (int i = 0; i < 72; i++) part[wave][i] = acc[i];
    }
    __syncthreads();
    if (t < 72)
        kv[((size_t)b * 64 + h) * 72 + t] = part[0][t] + part[1][t] + part[2][t] + part[3][t];
}

// ---------------- attn: out = (q.kv)_e / ((q.kv)_8 + 1e-15) ----------------
// h<32: q from fp32 qplane (sign-exact after qfix). h>=32: q from agg bf16.
// out (bf16) written into agg's dead k/v slots: map(o)=(o/16)*24+8+(o%16).
__global__ __launch_bounds__(256) void attn_out_kernel(
    const float* __restrict__ qplane, ushort* __restrict__ agg,
    const float* __restrict__ kv)
{
    const int pt = blockIdx.x, h = blockIdx.y, b = blockIdx.z, t = threadIdx.x;
    __shared__ float kvs[72];
    if (t < 72) kvs[t] = kv[((size_t)b * 64 + h) * 72 + t];
    __syncthreads();

    const bool lohead = (h < 32);
    const float* srcf = lohead
        ? qplane + ((size_t)(b * 256 + h * 8)) * P4096 : nullptr;
    const ushort* srcb = lohead ? nullptr
        : agg + ((size_t)(b * CQKV + (h - 32) * 24)) * P4096;

    int p = pt * 256 + t;
    float num[8]; float den = 0.0f;
    #pragma unroll
    for (int e = 0; e < 8; e++) num[e] = 0.0f;
    #pragma unroll
    for (int d = 0; d < 8; d++) {
        float q = lohead ? srcf[(size_t)d * P4096 + p]
                         : bf2f(srcb[(size_t)d * P4096 + p]);
        q = q > 0.0f ? q : 0.0f;
        #pragma unroll
        for (int e = 0; e < 8; e++) num[e] += q * kvs[d * 9 + e];
        den += q * kvs[d * 9 + 8];
    }
    float rd = 1.0f / (den + 1e-15f);
    // out ch o = h*8+e -> agg ch (h/2)*24 + 8 + (h%2)*8 + e
    ushort* dst = agg + ((size_t)(b * CQKV + (h / 2) * 24 + 8 + (h % 2) * 8)) * P4096 + p;
    #pragma unroll
    for (int e = 0; e < 8; e++)
        dst[(size_t)e * P4096] = f2bf(num[e] * rd);
}

// ---------------- GEMM3: y = W_proj(256x512) @ out[b](512x4096), bf16, BN ----------------
__global__ __launch_bounds__(256) void gemm_proj(
    const float* __restrict__ A,       // 256 x 512 fp32
    const ushort* __restrict__ Bagg,   // out in agg's k/v slots, map(k)=(k/16)*24+8+(k%16)
    float* __restrict__ Y,
    const float* __restrict__ bn_g, const float* __restrict__ bn_b,
    const float* __restrict__ bn_m, const float* __restrict__ bn_v)
{
    const int n0 = blockIdx.x * 64;
    const int m0 = blockIdx.y * 64;
    const int b  = blockIdx.z;
    const int t  = threadIdx.x;
    const int wave = t >> 6, lane = t & 63, quad = lane >> 4, l15 = lane & 15;
    const int K = 512;

    __shared__ __align__(16) ushort As[64][40];
    __shared__ __align__(16) ushort Bs[64][40];

    f32x4 acc[4];
    #pragma unroll
    for (int nt = 0; nt < 4; nt++)
        #pragma unroll
        for (int r = 0; r < 4; r++) acc[nt][r] = 0.0f;

    const int am = t >> 2;
    const int ak = (t & 3) * 8;
    const int bkk = t >> 3;           // 0..31
    const int bnn = (t & 7) * 8;      // 0..56

    for (int k0 = 0; k0 < K; k0 += 32) {
        float av[8];
        *(float4*)&av[0] = *(const float4*)(A + (size_t)(m0 + am) * K + k0 + ak);
        *(float4*)&av[4] = *(const float4*)(A + (size_t)(m0 + am) * K + k0 + ak + 4);
        int kk = k0 + bkk;
        int amch = (kk >> 4) * 24 + 8 + (kk & 15);
        uint4 bv = *(const uint4*)(Bagg + ((size_t)b * CQKV + amch) * P4096 + n0 + bnn);

        __syncthreads();
        {
            union { ushort us[8]; uint4 v; } ap;
            #pragma unroll
            for (int i = 0; i < 8; i++) ap.us[i] = f2bf(av[i]);
            *(uint4*)&As[am][ak] = ap.v;
        }
        {
            unsigned int bw[4] = {bv.x, bv.y, bv.z, bv.w};
            #pragma unroll
            for (int j = 0; j < 4; j++) {
                Bs[bnn + 2 * j + 0][bkk] = (ushort)(bw[j] & 0xffff);
                Bs[bnn + 2 * j + 1][bkk] = (ushort)(bw[j] >> 16);
            }
        }
        __syncthreads();

        bf16x8 af = *(const bf16x8*)&As[wave * 16 + l15][quad * 8];
        #pragma unroll
        for (int nt = 0; nt < 4; nt++) {
            bf16x8 bf = *(const bf16x8*)&Bs[nt * 16 + l15][quad * 8];
            acc[nt] = __builtin_amdgcn_mfma_f32_16x16x32_bf16(af, bf, acc[nt], 0, 0, 0);
        }
    }

    #pragma unroll
    for (int nt = 0; nt < 4; nt++) {
        #pragma unroll
        for (int r = 0; r < 4; r++) {
            int row = m0 + wave * 16 + quad * 4 + r;
            int col = n0 + nt * 16 + l15;
            float inv = bn_g[row] / sqrtf(bn_v[row] + 1e-5f);
            float v = acc[nt][r] * inv + (bn_b[row] - bn_m[row] * inv);
            Y[((size_t)b * 256 + row) * P4096 + col] = v;
        }
    }
}

// ---------------- launch ----------------
extern "C" void kernel_launch(void* const* d_in, const int* in_sizes, int n_in,
                              void* d_out, int out_size, void* d_ws, size_t ws_size,
                              hipStream_t stream) {
    const float* x      = (const float*)d_in[0];
    const float* w_qkv  = (const float*)d_in[1];
    const float* w_dw   = (const float*)d_in[2];
    const float* w_pw   = (const float*)d_in[3];
    const float* w_proj = (const float*)d_in[4];
    const float* bn_g   = (const float*)d_in[5];
    const float* bn_b   = (const float*)d_in[6];
    const float* bn_m   = (const float*)d_in[7];
    const float* bn_v   = (const float*)d_in[8];
    float* y = (float*)d_out;

    char* ws = (char*)d_ws;
    ushort* qkv_bf = (ushort*)(ws);                  // 96 MiB: bf16 768ch
    float*  qplane = (float*) (ws + 100663296);      // 64 MiB: fp32 q (heads 0-31)
    ushort* agg_bf = (ushort*)(ws + 167772160);      // 96 MiB: agg; k/v slots reused for out
    float*  kvbuf  = (float*)d_out;                  // 288 KB scratch; gemm_proj overwrites

    gemm_qkv<<<dim3(64, 12, NB), 256, 0, stream>>>(w_qkv, x, qkv_bf, qplane);

    qfix_kernel<<<65536, 256, 0, stream>>>(qplane, w_qkv, x);

    dwpw_kernel<<<dim3(8, 96, NB), 256, 0, stream>>>(qkv_bf, w_dw, w_pw, agg_bf);

    kv_kernel<<<dim3(64, NB), 256, 0, stream>>>(qkv_bf, agg_bf, kvbuf);

    attn_out_kernel<<<dim3(16, 64, NB), 256, 0, stream>>>(qplane, agg_bf, kvbuf);

    gemm_proj<<<dim3(64, 4, NB), 256, 0, stream>>>(
        w_proj, agg_bf, y, bn_g, bn_b, bn_m, bn_v);
}

// Round 6
// 502.757 us; speedup vs baseline: 1.3248x; 1.3248x over previous
//
#include <hip/hip_runtime.h>
#include <hip/hip_bf16.h>

// LiteMSA pipeline, MI355X gfx950.
// B=16, Cin=256, Cqkv=768, H=W=64 (P=4096), heads=64 (24 ch: q8,k8,v8),
// out 512 ch -> proj 256 ch + BN. Output y fp32.
//
// Numerics: q path (heads 0-31) fp32 via 3-term split-bf16 MFMA + fp64 fixup
// of |q|<1e-4 (degenerate-denominator relu sign flips). k/v rows single bf16
// MFMA (noise <=2e-5 at y). Row-permuted GEMM1: q rows in tiles 0-3 (split),
// k/v rows in tiles 0-7 of a second, cheaper kernel.
//
// ws (256 MiB exactly):
//   qkv_bf [0,96M)    bf16 768ch
//   qplane [96M,160M) fp32 256ch (q of heads 0-31), fixup'd in place
//   agg_bf [160M,256M) bf16 768ch; k/v slots (ch%24 in [8,24)) reused by attn
//                      for the 512-ch 'out' plane: map(o)=(o/16)*24+8+(o%16)
// d_out: kvbuf 288K scratch at head; gemm_proj (last, sole d_out writer)
// overwrites all of it.

#define NB 16
#define CQKV 768
#define P4096 4096

typedef __bf16 bf16x8 __attribute__((ext_vector_type(8)));
typedef float f32x4 __attribute__((ext_vector_type(4)));

__device__ __forceinline__ ushort f2bf(float f) {
    union { float f; unsigned int u; } x; x.f = f;
    unsigned int u = x.u;
    unsigned int r = (u + 0x7FFFu + ((u >> 16) & 1u)) >> 16;
    return (ushort)r;
}
__device__ __forceinline__ float bf2f(ushort u) {
    union { unsigned int u; float f; } x; x.u = ((unsigned int)u) << 16;
    return x.f;
}
__device__ __forceinline__ unsigned int pk2bf(float x, float y) {
    __hip_bfloat162 h = __float22bfloat162_rn(make_float2(x, y));  // v_cvt_pk_bf16_f32 (RNE)
    union { __hip_bfloat162 b; unsigned int u; } c; c.b = h; return c.u;
}
// 8 fp32 -> bf16 hi (one b128 LDS write)
__device__ __forceinline__ void stage_hi8(const float* v, ushort* dh) {
    union { unsigned int u[4]; uint4 q; } H;
    #pragma unroll
    for (int i = 0; i < 4; i++) H.u[i] = pk2bf(v[2 * i], v[2 * i + 1]);
    *(uint4*)dh = H.q;
}
// 8 fp32 -> bf16 hi + lo (two b128 LDS writes)
__device__ __forceinline__ void stage_hilo8(const float* v, ushort* dh, ushort* dl) {
    union { unsigned int u[4]; uint4 q; } H, L;
    #pragma unroll
    for (int i = 0; i < 4; i++) {
        unsigned int h = pk2bf(v[2 * i], v[2 * i + 1]);
        H.u[i] = h;
        float f0 = __uint_as_float(h << 16);
        float f1 = __uint_as_float(h & 0xffff0000u);
        L.u[i] = pk2bf(v[2 * i] - f0, v[2 * i + 1] - f1);
    }
    *(uint4*)dh = H.q;
    *(uint4*)dl = L.q;
}

// ---------------- GEMM1a: q rows (virt 0..255; phys=(v/8)*24+v%8), 3-term split ----------------
// BM=BN=64, BK=32, 256 thr = 4 waves. MFMA 16x16x32 bf16.
// A-frag: m=lane&15, k=quad*8+j ; B-frag: n=lane&15, k=quad*8+j (Bs [n][k]).
// D: col=lane&15, row=quad*4+reg.
// B staged by column loads: thread -> (n=t&63, kg=(t>>6)*8), one ds_write_b128,
// conflict-free on stride-40-ushort rows.
__global__ __launch_bounds__(256) void gemm_qkv_q(
    const float* __restrict__ A,      // 768 x 256 fp32 (phys rows)
    const float* __restrict__ X,      // b-strided 256 x 4096 fp32
    ushort* __restrict__ Cbf,         // b-strided 768 x 4096 bf16 (phys rows)
    float*  __restrict__ qplane)      // b-strided 256 x 4096 fp32 (virt q rows)
{
    const int n0 = blockIdx.x * 64;
    const int m0 = blockIdx.y * 64;   // virt q-row base
    const int b  = blockIdx.z;
    const int t  = threadIdx.x;
    const int wave = t >> 6, lane = t & 63, quad = lane >> 4, l15 = lane & 15;

    __shared__ __align__(16) ushort AsH[64][40];
    __shared__ __align__(16) ushort AsL[64][40];
    __shared__ __align__(16) ushort BsH[64][40];
    __shared__ __align__(16) ushort BsL[64][40];

    f32x4 acc[4];
    #pragma unroll
    for (int nt = 0; nt < 4; nt++)
        #pragma unroll
        for (int r = 0; r < 4; r++) acc[nt][r] = 0.0f;

    const int am = t >> 2, ak = (t & 3) * 8;
    const int arow_v = m0 + am;
    const int arow_p = (arow_v >> 3) * 24 + (arow_v & 7);
    const int bn = t & 63, kg = (t >> 6) * 8;

    for (int k0 = 0; k0 < 256; k0 += 32) {
        float av[8];
        *(float4*)&av[0] = *(const float4*)(A + (size_t)arow_p * 256 + k0 + ak);
        *(float4*)&av[4] = *(const float4*)(A + (size_t)arow_p * 256 + k0 + ak + 4);
        float bv[8];
        #pragma unroll
        for (int i = 0; i < 8; i++)
            bv[i] = X[((size_t)b * 256 + k0 + kg + i) * P4096 + n0 + bn];

        __syncthreads();
        stage_hilo8(av, &AsH[am][ak], &AsL[am][ak]);
        stage_hilo8(bv, &BsH[bn][kg], &BsL[bn][kg]);
        __syncthreads();

        bf16x8 afh = *(const bf16x8*)&AsH[wave * 16 + l15][quad * 8];
        bf16x8 afl = *(const bf16x8*)&AsL[wave * 16 + l15][quad * 8];
        #pragma unroll
        for (int nt = 0; nt < 4; nt++) {
            bf16x8 bfh = *(const bf16x8*)&BsH[nt * 16 + l15][quad * 8];
            bf16x8 bfl = *(const bf16x8*)&BsL[nt * 16 + l15][quad * 8];
            acc[nt] = __builtin_amdgcn_mfma_f32_16x16x32_bf16(afh, bfh, acc[nt], 0, 0, 0);
            acc[nt] = __builtin_amdgcn_mfma_f32_16x16x32_bf16(afl, bfh, acc[nt], 0, 0, 0);
            acc[nt] = __builtin_amdgcn_mfma_f32_16x16x32_bf16(afh, bfl, acc[nt], 0, 0, 0);
        }
    }

    #pragma unroll
    for (int nt = 0; nt < 4; nt++) {
        #pragma unroll
        for (int r = 0; r < 4; r++) {
            int rv = m0 + wave * 16 + quad * 4 + r;
            int rp = (rv >> 3) * 24 + (rv & 7);
            int col = n0 + nt * 16 + l15;
            float v = acc[nt][r];
            Cbf[((size_t)b * CQKV + rp) * P4096 + col] = f2bf(v);
            qplane[((size_t)b * 256 + rv) * P4096 + col] = v;
        }
    }
}

// ---------------- GEMM1b: k/v rows (virt2 0..511; phys=(v/16)*24+8+v%16), single MFMA ----------------
__global__ __launch_bounds__(256) void gemm_qkv_kv(
    const float* __restrict__ A, const float* __restrict__ X,
    ushort* __restrict__ Cbf)
{
    const int n0 = blockIdx.x * 64;
    const int m0 = blockIdx.y * 64;   // virt2 base
    const int b  = blockIdx.z;
    const int t  = threadIdx.x;
    const int wave = t >> 6, lane = t & 63, quad = lane >> 4, l15 = lane & 15;

    __shared__ __align__(16) ushort As[64][40];
    __shared__ __align__(16) ushort Bs[64][40];

    f32x4 acc[4];
    #pragma unroll
    for (int nt = 0; nt < 4; nt++)
        #pragma unroll
        for (int r = 0; r < 4; r++) acc[nt][r] = 0.0f;

    const int am = t >> 2, ak = (t & 3) * 8;
    const int arow_v = m0 + am;
    const int arow_p = (arow_v >> 4) * 24 + 8 + (arow_v & 15);
    const int bn = t & 63, kg = (t >> 6) * 8;

    for (int k0 = 0; k0 < 256; k0 += 32) {
        float av[8];
        *(float4*)&av[0] = *(const float4*)(A + (size_t)arow_p * 256 + k0 + ak);
        *(float4*)&av[4] = *(const float4*)(A + (size_t)arow_p * 256 + k0 + ak + 4);
        float bv[8];
        #pragma unroll
        for (int i = 0; i < 8; i++)
            bv[i] = X[((size_t)b * 256 + k0 + kg + i) * P4096 + n0 + bn];

        __syncthreads();
        stage_hi8(av, &As[am][ak]);
        stage_hi8(bv, &Bs[bn][kg]);
        __syncthreads();

        bf16x8 af = *(const bf16x8*)&As[wave * 16 + l15][quad * 8];
        #pragma unroll
        for (int nt = 0; nt < 4; nt++) {
            bf16x8 bf = *(const bf16x8*)&Bs[nt * 16 + l15][quad * 8];
            acc[nt] = __builtin_amdgcn_mfma_f32_16x16x32_bf16(af, bf, acc[nt], 0, 0, 0);
        }
    }

    #pragma unroll
    for (int nt = 0; nt < 4; nt++) {
        #pragma unroll
        for (int r = 0; r < 4; r++) {
            int rv = m0 + wave * 16 + quad * 4 + r;
            int rp = (rv >> 4) * 24 + 8 + (rv & 15);
            int col = n0 + nt * 16 + l15;
            Cbf[((size_t)b * CQKV + rp) * P4096 + col] = f2bf(acc[nt][r]);
        }
    }
}

// ---------------- qfix: recompute |q|<1e-4 in fp64 (kills relu sign flips) ----------------
__global__ __launch_bounds__(256) void qfix_kernel(
    float* __restrict__ qplane, const float* __restrict__ w_qkv,
    const float* __restrict__ x)
{
    size_t i = (size_t)blockIdx.x * 256 + threadIdx.x;  // over 16*256*4096
    float q = qplane[i];
    if (fabsf(q) >= 1e-4f) return;
    int p   = (int)(i & 4095);
    int qch = (int)((i >> 12) & 255);
    int b   = (int)(i >> 20);
    int row = (qch >> 3) * 24 + (qch & 7);
    const float* wr = w_qkv + (size_t)row * 256;
    const float* xr = x + (size_t)b * 256 * P4096 + p;
    double s = 0.0;
    for (int c = 0; c < 256; c++)
        s += (double)wr[c] * (double)xr[(size_t)c * P4096];
    qplane[i] = (float)s;
}

// ---------------- dw 3x3 + grouped pw (bf16; feeds only heads 32-63) ----------------
__global__ __launch_bounds__(256) void dwpw_kernel(
    const ushort* __restrict__ qkv, const float* __restrict__ wdw,
    const float* __restrict__ wpw, ushort* __restrict__ agg)
{
    const int rt = blockIdx.x;    // 0..7
    const int g  = blockIdx.y;    // 0..95
    const int b  = blockIdx.z;
    const int t  = threadIdx.x;
    const int r0 = rt * 8;
    const int cg = g * 8;

    __shared__ __align__(16) float tile[8][10][72];  // data cols 4..67, halo 3 & 68
    __shared__ float wdw_s[8][9];
    __shared__ float wpw_s[8][8];

    if (t < 72) wdw_s[t / 9][t % 9] = wdw[(size_t)(cg + t / 9) * 9 + t % 9];
    else if (t < 136) { int i = (t - 72) >> 3, j = (t - 72) & 7; wpw_s[i][j] = wpw[(size_t)(cg + i) * 8 + j]; }
    if (t < 80) { int c = t / 10, rr = t % 10; tile[c][rr][3] = 0.0f; tile[c][rr][68] = 0.0f; }

    const ushort* src = qkv + ((size_t)(b * CQKV + cg)) * P4096;
    #pragma unroll
    for (int i = 0; i < 5; i++) {
        int idx = t + i * 256;               // 0..1279
        int c = idx / 160; int rem = idx - c * 160;
        int rr = rem >> 4; int nn = (rem & 15) * 4;
        int grow = r0 - 1 + rr;
        float4 v = make_float4(0.f, 0.f, 0.f, 0.f);
        if (grow >= 0 && grow < 64) {
            uint2 u = *(const uint2*)(src + (size_t)c * P4096 + grow * 64 + nn);
            v.x = bf2f((ushort)(u.x & 0xffff));
            v.y = bf2f((ushort)(u.x >> 16));
            v.z = bf2f((ushort)(u.y & 0xffff));
            v.w = bf2f((ushort)(u.y >> 16));
        }
        *(float4*)&tile[c][rr][4 + nn] = v;
    }
    __syncthreads();

    #pragma unroll
    for (int i = 0; i < 2; i++) {
        int pos = t + i * 256;
        int pr = pos >> 6, pc = pos & 63;
        float dwv[8];
        #pragma unroll
        for (int c = 0; c < 8; c++) {
            float s = 0.0f;
            #pragma unroll
            for (int dy = 0; dy < 3; dy++)
                #pragma unroll
                for (int dx = 0; dx < 3; dx++)
                    s += wdw_s[c][dy * 3 + dx] * tile[c][pr + dy][pc + 3 + dx];
            dwv[c] = s;
        }
        size_t obase = ((size_t)(b * CQKV + cg)) * P4096 + (size_t)(r0 + pr) * 64 + pc;
        #pragma unroll
        for (int oi = 0; oi < 8; oi++) {
            float s = 0.0f;
            #pragma unroll
            for (int j = 0; j < 8; j++) s += wpw_s[oi][j] * dwv[j];
            agg[obase + (size_t)oi * P4096] = f2bf(s);
        }
    }
}

// ---------------- kv[b,h,d,e] = sum_p relu(k_d)*v_e  (v_8 = 1) ----------------
__global__ __launch_bounds__(256) void kv_kernel(
    const ushort* __restrict__ qkv, const ushort* __restrict__ agg,
    float* __restrict__ kv)
{
    const int h = blockIdx.x, b = blockIdx.y, t = threadIdx.x;
    const ushort* src = (h < 32)
        ? qkv + ((size_t)(b * CQKV + h * 24)) * P4096
        : agg + ((size_t)(b * CQKV + (h - 32) * 24)) * P4096;

    float acc[72];
    #pragma unroll
    for (int i = 0; i < 72; i++) acc[i] = 0.0f;

    for (int pi = 0; pi < 16; pi++) {
        int p = t + pi * 256;
        float kvv[8], vv[8];
        #pragma unroll
        for (int d = 0; d < 8; d++) {
            float xk = bf2f(src[(size_t)(8 + d) * P4096 + p]);
            kvv[d] = xk > 0.0f ? xk : 0.0f;
        }
        #pragma unroll
        for (int e = 0; e < 8; e++) vv[e] = bf2f(src[(size_t)(16 + e) * P4096 + p]);
        #pragma unroll
        for (int d = 0; d < 8; d++) {
            #pragma unroll
            for (int e = 0; e < 8; e++) acc[d * 9 + e] += kvv[d] * vv[e];
            acc[d * 9 + 8] += kvv[d];
        }
    }

    #pragma unroll
    for (int i = 0; i < 72; i++) {
        float v = acc[i];
        #pragma unroll
        for (int off = 32; off > 0; off >>= 1) v += __shfl_xor(v, off, 64);
        acc[i] = v;
    }
    __shared__ float part[4][72];
    int wave = t >> 6, lane = t & 63;
    if (lane == 0) {
        #pragma unroll
        for (int i = 0; i < 72; i++) part[wave][i] = acc[i];
    }
    __syncthreads();
    if (t < 72)
        kv[((size_t)b * 64 + h) * 72 + t] = part[0][t] + part[1][t] + part[2][t] + part[3][t];
}

// ---------------- attn: out = (q.kv)_e / ((q.kv)_8 + 1e-15) ----------------
// h<32: q from fp32 qplane (sign-exact after qfix). h>=32: q from agg bf16.
// out (bf16) written into agg's dead k/v slots: map(o)=(o/16)*24+8+(o%16).
__global__ __launch_bounds__(256) void attn_out_kernel(
    const float* __restrict__ qplane, ushort* __restrict__ agg,
    const float* __restrict__ kv)
{
    const int pt = blockIdx.x, h = blockIdx.y, b = blockIdx.z, t = threadIdx.x;
    __shared__ float kvs[72];
    if (t < 72) kvs[t] = kv[((size_t)b * 64 + h) * 72 + t];
    __syncthreads();

    const bool lohead = (h < 32);
    const float* srcf = lohead
        ? qplane + ((size_t)(b * 256 + h * 8)) * P4096 : nullptr;
    const ushort* srcb = lohead ? nullptr
        : agg + ((size_t)(b * CQKV + (h - 32) * 24)) * P4096;

    int p = pt * 256 + t;
    float num[8]; float den = 0.0f;
    #pragma unroll
    for (int e = 0; e < 8; e++) num[e] = 0.0f;
    #pragma unroll
    for (int d = 0; d < 8; d++) {
        float q = lohead ? srcf[(size_t)d * P4096 + p]
                         : bf2f(srcb[(size_t)d * P4096 + p]);
        q = q > 0.0f ? q : 0.0f;
        #pragma unroll
        for (int e = 0; e < 8; e++) num[e] += q * kvs[d * 9 + e];
        den += q * kvs[d * 9 + 8];
    }
    float rd = 1.0f / (den + 1e-15f);
    ushort* dst = agg + ((size_t)(b * CQKV + (h / 2) * 24 + 8 + (h % 2) * 8)) * P4096 + p;
    #pragma unroll
    for (int e = 0; e < 8; e++)
        dst[(size_t)e * P4096] = f2bf(num[e] * rd);
}

// ---------------- GEMM3: y = W_proj(256x512) @ out[b](512x4096), bf16, BN ----------------
__global__ __launch_bounds__(256) void gemm_proj(
    const float* __restrict__ A,       // 256 x 512 fp32
    const ushort* __restrict__ Bagg,   // out in agg's k/v slots, map(k)=(k/16)*24+8+(k%16)
    float* __restrict__ Y,
    const float* __restrict__ bn_g, const float* __restrict__ bn_b,
    const float* __restrict__ bn_m, const float* __restrict__ bn_v)
{
    const int n0 = blockIdx.x * 64;
    const int m0 = blockIdx.y * 64;
    const int b  = blockIdx.z;
    const int t  = threadIdx.x;
    const int wave = t >> 6, lane = t & 63, quad = lane >> 4, l15 = lane & 15;

    __shared__ __align__(16) ushort As[64][40];
    __shared__ __align__(16) ushort Bs[64][40];

    f32x4 acc[4];
    #pragma unroll
    for (int nt = 0; nt < 4; nt++)
        #pragma unroll
        for (int r = 0; r < 4; r++) acc[nt][r] = 0.0f;

    const int am = t >> 2, ak = (t & 3) * 8;
    const int bn = t & 63, kg = (t >> 6) * 8;

    for (int k0 = 0; k0 < 512; k0 += 32) {
        float av[8];
        *(float4*)&av[0] = *(const float4*)(A + (size_t)(m0 + am) * 512 + k0 + ak);
        *(float4*)&av[4] = *(const float4*)(A + (size_t)(m0 + am) * 512 + k0 + ak + 4);
        ushort bu[8];
        #pragma unroll
        for (int i = 0; i < 8; i++) {
            int kk = k0 + kg + i;
            int amch = (kk >> 4) * 24 + 8 + (kk & 15);
            bu[i] = Bagg[((size_t)b * CQKV + amch) * P4096 + n0 + bn];
        }

        __syncthreads();
        stage_hi8(av, &As[am][ak]);
        {
            union { ushort us[8]; uint4 q; } Bp;
            #pragma unroll
            for (int i = 0; i < 8; i++) Bp.us[i] = bu[i];
            *(uint4*)&Bs[bn][kg] = Bp.q;
        }
        __syncthreads();

        bf16x8 af = *(const bf16x8*)&As[wave * 16 + l15][quad * 8];
        #pragma unroll
        for (int nt = 0; nt < 4; nt++) {
            bf16x8 bf = *(const bf16x8*)&Bs[nt * 16 + l15][quad * 8];
            acc[nt] = __builtin_amdgcn_mfma_f32_16x16x32_bf16(af, bf, acc[nt], 0, 0, 0);
        }
    }

    #pragma unroll
    for (int nt = 0; nt < 4; nt++) {
        #pragma unroll
        for (int r = 0; r < 4; r++) {
            int row = m0 + wave * 16 + quad * 4 + r;
            int col = n0 + nt * 16 + l15;
            float inv = bn_g[row] / sqrtf(bn_v[row] + 1e-5f);
            float v = acc[nt][r] * inv + (bn_b[row] - bn_m[row] * inv);
            Y[((size_t)b * 256 + row) * P4096 + col] = v;
        }
    }
}

// ---------------- launch ----------------
extern "C" void kernel_launch(void* const* d_in, const int* in_sizes, int n_in,
                              void* d_out, int out_size, void* d_ws, size_t ws_size,
                              hipStream_t stream) {
    const float* x      = (const float*)d_in[0];
    const float* w_qkv  = (const float*)d_in[1];
    const float* w_dw   = (const float*)d_in[2];
    const float* w_pw   = (const float*)d_in[3];
    const float* w_proj = (const float*)d_in[4];
    const float* bn_g   = (const float*)d_in[5];
    const float* bn_b   = (const float*)d_in[6];
    const float* bn_m   = (const float*)d_in[7];
    const float* bn_v   = (const float*)d_in[8];
    float* y = (float*)d_out;

    char* ws = (char*)d_ws;
    ushort* qkv_bf = (ushort*)(ws);                  // 96 MiB: bf16 768ch
    float*  qplane = (float*) (ws + 100663296);      // 64 MiB: fp32 q (heads 0-31)
    ushort* agg_bf = (ushort*)(ws + 167772160);      // 96 MiB: agg; k/v slots reused for out
    float*  kvbuf  = (float*)d_out;                  // 288 KB scratch; gemm_proj overwrites

    gemm_qkv_q<<<dim3(64, 4, NB), 256, 0, stream>>>(w_qkv, x, qkv_bf, qplane);
    gemm_qkv_kv<<<dim3(64, 8, NB), 256, 0, stream>>>(w_qkv, x, qkv_bf);

    qfix_kernel<<<65536, 256, 0, stream>>>(qplane, w_qkv, x);

    dwpw_kernel<<<dim3(8, 96, NB), 256, 0, stream>>>(qkv_bf, w_dw, w_pw, agg_bf);

    kv_kernel<<<dim3(64, NB), 256, 0, stream>>>(qkv_bf, agg_bf, kvbuf);

    attn_out_kernel<<<dim3(16, 64, NB), 256, 0, stream>>>(qplane, agg_bf, kvbuf);

    gemm_proj<<<dim3(64, 4, NB), 256, 0, stream>>>(
        w_proj, agg_bf, y, bn_g, bn_b, bn_m, bn_v);
}